// Round 1
// baseline (790.654 us; speedup 1.0000x reference)
//
#include <hip/hip_runtime.h>
#include <math.h>

#define HH 64
#define PTILE 16
#define NCOMP 12
#define PI_F 3.14159265358979323846f

// Jet component layout (c index, per point per neuron):
//  interior (x,t):  0:v 1:x 2:t 3:xx 4:xt 5:tt
//  boundary (1,t):  6:v 7:x 8:t 9:xt 10:tt 11:xtt

#define F4(A, S) { A.x = fmaf((S), wv.x, A.x); A.y = fmaf((S), wv.y, A.y); \
                   A.z = fmaf((S), wv.z, A.z); A.w = fmaf((S), wv.w, A.w); }

#define COMPOSE(CX, JJ) do { \
    const int j = j0 + (JJ); \
    const float bb = bs[j]; \
    float* hp = &hbuf[(j * PTILE + p) * NCOMP]; \
    const float zv  = acc[0].CX + bb; \
    const float zx  = acc[1].CX; \
    const float zt  = acc[2].CX; \
    const float zxx = acc[3].CX; \
    const float zxt = acc[4].CX; \
    const float ztt = acc[5].CX; \
    const float a   = tanhf(zv); \
    const float d1  = 1.f - a * a; \
    const float d2  = -2.f * a * d1; \
    const float zvB   = acc[6].CX + bb; \
    const float zxB   = acc[7].CX; \
    const float ztB   = acc[8].CX; \
    const float zxtB  = acc[9].CX; \
    const float zttB  = acc[10].CX; \
    const float zxttB = acc[11].CX; \
    const float aB  = tanhf(zvB); \
    const float e1  = 1.f - aB * aB; \
    const float e2  = -2.f * aB * e1; \
    const float e3  = -2.f * (e1 * e1 + aB * e2); \
    float4 o0, o1, o2; \
    o0.x = a; \
    o0.y = d1 * zx; \
    o0.z = d1 * zt; \
    o0.w = fmaf(d2 * zx, zx, d1 * zxx); \
    o1.x = fmaf(d2 * zx, zt, d1 * zxt); \
    o1.y = fmaf(d2 * zt, zt, d1 * ztt); \
    o1.z = aB; \
    o1.w = e1 * zxB; \
    o2.x = e1 * ztB; \
    o2.y = fmaf(e2 * zxB, ztB, e1 * zxtB); \
    o2.z = fmaf(e2 * ztB, ztB, e1 * zttB); \
    o2.w = e3 * zxB * ztB * ztB + e2 * (2.f * zxtB * ztB + zxB * zttB) + e1 * zxttB; \
    *(float4*)(hp)     = o0; \
    *(float4*)(hp + 4) = o1; \
    *(float4*)(hp + 8) = o2; \
} while (0)

__global__ __launch_bounds__(256) void pinn_main(
    const float* __restrict__ pts,
    const float* __restrict__ W1, const float* __restrict__ b1,
    const float* __restrict__ W2, const float* __restrict__ b2,
    const float* __restrict__ W3, const float* __restrict__ b3,
    const float* __restrict__ Wo,
    float* __restrict__ partial)
{
    __shared__ float hbuf[HH * PTILE * NCOMP];   // [k][p][c], 48 KB
    __shared__ float ubuf[PTILE * NCOMP];
    __shared__ float rbuf[PTILE];

    const int tid = threadIdx.x;
    const int p   = tid & 15;      // point within tile
    const int jg  = tid >> 4;      // neuron group 0..15
    const int j0  = jg * 4;        // 4 neurons per thread

    const int ptIdx = blockIdx.x * PTILE + p;
    const float px = pts[2 * ptIdx];
    const float pt = pts[2 * ptIdx + 1];

    // ---------------- layer 1 (2 -> 64) ----------------
    #pragma unroll
    for (int jj = 0; jj < 4; ++jj) {
        const int j = j0 + jj;
        const float w0 = W1[j];        // d z / d x
        const float w1 = W1[HH + j];   // d z / d t
        const float bb = b1[j];
        float* hp = &hbuf[(j * PTILE + p) * NCOMP];
        // interior jet at (x,t): z = {zv, w0, w1, 0,0,0}
        {
            const float zv = fmaf(px, w0, fmaf(pt, w1, bb));
            const float a  = tanhf(zv);
            const float d1 = 1.f - a * a;
            const float d2 = -2.f * a * d1;
            hp[0] = a;
            hp[1] = d1 * w0;
            hp[2] = d1 * w1;
            hp[3] = d2 * w0 * w0;
            hp[4] = d2 * w0 * w1;
            hp[5] = d2 * w1 * w1;
        }
        // boundary jet at (1,t): z = {zv, w0, w1, 0(xt),0(tt),0(xtt)}
        {
            const float zv = w0 + fmaf(pt, w1, bb);
            const float a  = tanhf(zv);
            const float d1 = 1.f - a * a;
            const float d2 = -2.f * a * d1;
            const float d3 = -2.f * (d1 * d1 + a * d2);
            hp[6]  = a;
            hp[7]  = d1 * w0;
            hp[8]  = d1 * w1;
            hp[9]  = d2 * w0 * w1;
            hp[10] = d2 * w1 * w1;
            hp[11] = d3 * w0 * w1 * w1;
        }
    }
    __syncthreads();

    // ---------------- hidden layers 2 and 3 (64 -> 64) ----------------
    #pragma unroll 1
    for (int layer = 0; layer < 2; ++layer) {
        const float* __restrict__ W  = layer ? W3 : W2;
        const float* __restrict__ bs = layer ? b3 : b2;

        float4 acc[NCOMP];
        #pragma unroll
        for (int c = 0; c < NCOMP; ++c) acc[c] = make_float4(0.f, 0.f, 0.f, 0.f);

        #pragma unroll 4
        for (int k = 0; k < HH; ++k) {
            const float4 wv = *(const float4*)(W + k * HH + j0);
            const float* hp = &hbuf[(k * PTILE + p) * NCOMP];
            const float4 h0 = *(const float4*)(hp);
            const float4 h1 = *(const float4*)(hp + 4);
            const float4 h2 = *(const float4*)(hp + 8);
            F4(acc[0], h0.x) F4(acc[1], h0.y) F4(acc[2],  h0.z) F4(acc[3],  h0.w)
            F4(acc[4], h1.x) F4(acc[5], h1.y) F4(acc[6],  h1.z) F4(acc[7],  h1.w)
            F4(acc[8], h2.x) F4(acc[9], h2.y) F4(acc[10], h2.z) F4(acc[11], h2.w)
        }
        __syncthreads();   // everyone done reading hbuf
        COMPOSE(x, 0);
        COMPOSE(y, 1);
        COMPOSE(z, 2);
        COMPOSE(w, 3);
        __syncthreads();   // new hbuf ready
    }

    // ---------------- output layer (64 -> 1), 12 comps x 16 points ----------------
    if (tid < PTILE * NCOMP) {
        const int p2 = tid & 15;
        const int c2 = tid >> 4;   // 0..11
        float s = 0.f;
        #pragma unroll 8
        for (int k = 0; k < HH; ++k)
            s = fmaf(hbuf[(k * PTILE + p2) * NCOMP + c2], Wo[k], s);
        ubuf[p2 * NCOMP + c2] = s;
    }
    __syncthreads();

    // ---------------- residual per point ----------------
    if (tid < PTILE) {
        const int pp = tid;
        const float* u = &ubuf[pp * NCOMP];
        const int gIdx = blockIdx.x * PTILE + pp;
        const float x = pts[2 * gIdx];
        const float t = pts[2 * gIdx + 1];

        const float D   = u[0] - u[6] - u[7];       // u - u(1,t) - u_x(1,t)
        const float Dx  = u[1];
        const float Dt  = u[2] - u[8] - u[9];
        const float Dxx = u[3];
        const float Dxt = u[4];
        const float Dtt = u[5] - u[10] - u[11];

        const float s  = sinf(PI_F * t);
        const float cc = cosf(PI_F * t);
        const float A  = t * t - t,  Ap = 2.f * t - 1.f;
        const float B  = x * x - x,  Bp = 2.f * x - 1.f;

        const float psi    = 2.f * x * s + A * B * D;
        const float psi_x  = 2.f * s + A * (Bp * D + B * Dx);
        const float psi_xx = A * (2.f * D + 2.f * Bp * Dx + B * Dxx);
        const float psi_xt = 2.f * PI_F * cc + Ap * (Bp * D + B * Dx)
                           + A * (Bp * Dt + B * Dxt);
        const float psi_tt = -2.f * PI_F * PI_F * x * s + 2.f * B * D
                           + 2.f * Ap * B * Dt + A * B * Dtt;

        const float forcing = s * (2.f - PI_F * PI_F * x * x + 2.f * x * x * x * s);
        const float res = psi_xx + 2.f * psi_xt + psi_tt + psi * psi_x - forcing;
        rbuf[pp] = fabsf(res);
    }
    __syncthreads();

    if (tid == 0) {
        float s = 0.f;
        #pragma unroll
        for (int i = 0; i < PTILE; ++i) s += rbuf[i];
        partial[blockIdx.x] = s;
    }
}

__global__ __launch_bounds__(256) void pinn_reduce(
    const float* __restrict__ partial, float* __restrict__ out,
    int nblocks, float invN)
{
    __shared__ float sd[256];
    float s = 0.f;
    for (int i = threadIdx.x; i < nblocks; i += 256) s += partial[i];
    sd[threadIdx.x] = s;
    __syncthreads();
    #pragma unroll
    for (int off = 128; off > 0; off >>= 1) {
        if (threadIdx.x < off) sd[threadIdx.x] += sd[threadIdx.x + off];
        __syncthreads();
    }
    if (threadIdx.x == 0) out[0] = sd[0] * invN;
}

extern "C" void kernel_launch(void* const* d_in, const int* in_sizes, int n_in,
                              void* d_out, int out_size, void* d_ws, size_t ws_size,
                              hipStream_t stream)
{
    const float* pts = (const float*)d_in[0];
    const float* W1  = (const float*)d_in[1];
    const float* b1  = (const float*)d_in[2];
    const float* W2  = (const float*)d_in[3];
    const float* b2  = (const float*)d_in[4];
    const float* W3  = (const float*)d_in[5];
    const float* b3  = (const float*)d_in[6];
    const float* Wo  = (const float*)d_in[7];
    // d_in[8] = bo: constant offset cancels in (u - u(1,t)) and has zero
    // derivative -> does not affect the residual at all.

    const int nPts    = in_sizes[0] / 2;          // 262144
    const int nBlocks = nPts / PTILE;             // 16384

    float* partial = (float*)d_ws;                // nBlocks * 4 B = 64 KB

    pinn_main<<<nBlocks, 256, 0, stream>>>(pts, W1, b1, W2, b2, W3, b3, Wo, partial);
    pinn_reduce<<<1, 256, 0, stream>>>(partial, (float*)d_out, nBlocks,
                                       1.f / (float)nPts);
}

// Round 2
// 681.459 us; speedup vs baseline: 1.1602x; 1.1602x over previous
//
#include <hip/hip_runtime.h>
#include <math.h>

#define HH 64
#define PTILE 16
#define NCOMP 12
#define PI_F 3.14159265358979323846f

// Jet component layout (c index, per point per neuron):
//  interior (x,t):  0:v 1:x 2:t 3:xx 4:xt 5:tt
//  boundary (1,t):  6:v 7:x 8:t 9:xt 10:tt 11:xtt
//
// LDS layout: hb4[cg][k][p] (float4), cg in {0,1,2} = comps 4cg..4cg+3.
// A quarter-wave (16 lanes, one jg group) reads/writes a contiguous 256B
// segment -> conflict-free ds_read_b128 / ds_write_b128.

#define HB4(cg, k, p) hb4[((cg) * HH + (k)) * PTILE + (p)]

#define F4(A, S) { A.x = fmaf((S), wv.x, A.x); A.y = fmaf((S), wv.y, A.y); \
                   A.z = fmaf((S), wv.z, A.z); A.w = fmaf((S), wv.w, A.w); }

#define COMPOSE(CX, JJ) do { \
    const int j = j0 + (JJ); \
    const float bb = bs[j]; \
    const float zv  = acc[0].CX + bb; \
    const float zx  = acc[1].CX; \
    const float zt  = acc[2].CX; \
    const float zxx = acc[3].CX; \
    const float zxt = acc[4].CX; \
    const float ztt = acc[5].CX; \
    const float a   = tanhf(zv); \
    const float d1  = 1.f - a * a; \
    const float d2  = -2.f * a * d1; \
    const float zvB   = acc[6].CX + bb; \
    const float zxB   = acc[7].CX; \
    const float ztB   = acc[8].CX; \
    const float zxtB  = acc[9].CX; \
    const float zttB  = acc[10].CX; \
    const float zxttB = acc[11].CX; \
    const float aB  = tanhf(zvB); \
    const float e1  = 1.f - aB * aB; \
    const float e2  = -2.f * aB * e1; \
    const float e3  = -2.f * (e1 * e1 + aB * e2); \
    float4 o0, o1, o2; \
    o0.x = a; \
    o0.y = d1 * zx; \
    o0.z = d1 * zt; \
    o0.w = fmaf(d2 * zx, zx, d1 * zxx); \
    o1.x = fmaf(d2 * zx, zt, d1 * zxt); \
    o1.y = fmaf(d2 * zt, zt, d1 * ztt); \
    o1.z = aB; \
    o1.w = e1 * zxB; \
    o2.x = e1 * ztB; \
    o2.y = fmaf(e2 * zxB, ztB, e1 * zxtB); \
    o2.z = fmaf(e2 * ztB, ztB, e1 * zttB); \
    o2.w = e3 * zxB * ztB * ztB + e2 * (2.f * zxtB * ztB + zxB * zttB) + e1 * zxttB; \
    HB4(0, j, p) = o0; \
    HB4(1, j, p) = o1; \
    HB4(2, j, p) = o2; \
} while (0)

__global__ __launch_bounds__(256) void pinn_main(
    const float* __restrict__ pts,
    const float* __restrict__ W1, const float* __restrict__ b1,
    const float* __restrict__ W2, const float* __restrict__ b2,
    const float* __restrict__ W3, const float* __restrict__ b3,
    const float* __restrict__ Wo,
    float* __restrict__ partial)
{
    __shared__ float4 hb4[3 * HH * PTILE];       // 48 KB
    __shared__ float ubuf[PTILE * NCOMP];
    __shared__ float rbuf[PTILE];

    const int tid = threadIdx.x;
    const int p   = tid & 15;      // point within tile
    const int jg  = tid >> 4;      // neuron group 0..15
    const int j0  = jg * 4;        // 4 neurons per thread

    const int ptIdx = blockIdx.x * PTILE + p;
    const float px = pts[2 * ptIdx];
    const float pt = pts[2 * ptIdx + 1];

    // ---------------- layer 1 (2 -> 64) ----------------
    #pragma unroll
    for (int jj = 0; jj < 4; ++jj) {
        const int j = j0 + jj;
        const float w0 = W1[j];        // d z / d x
        const float w1 = W1[HH + j];   // d z / d t
        const float bb = b1[j];
        float4 o0, o1, o2;
        // interior jet at (x,t)
        {
            const float zv = fmaf(px, w0, fmaf(pt, w1, bb));
            const float a  = tanhf(zv);
            const float d1 = 1.f - a * a;
            const float d2 = -2.f * a * d1;
            o0.x = a;
            o0.y = d1 * w0;
            o0.z = d1 * w1;
            o0.w = d2 * w0 * w0;
            o1.x = d2 * w0 * w1;
            o1.y = d2 * w1 * w1;
        }
        // boundary jet at (1,t)
        {
            const float zv = w0 + fmaf(pt, w1, bb);
            const float a  = tanhf(zv);
            const float d1 = 1.f - a * a;
            const float d2 = -2.f * a * d1;
            const float d3 = -2.f * (d1 * d1 + a * d2);
            o1.z = a;
            o1.w = d1 * w0;
            o2.x = d1 * w1;
            o2.y = d2 * w0 * w1;
            o2.z = d2 * w1 * w1;
            o2.w = d3 * w0 * w1 * w1;
        }
        HB4(0, j, p) = o0;
        HB4(1, j, p) = o1;
        HB4(2, j, p) = o2;
    }
    __syncthreads();

    // ---------------- hidden layers 2 and 3 (64 -> 64) ----------------
    #pragma unroll 1
    for (int layer = 0; layer < 2; ++layer) {
        const float* __restrict__ W  = layer ? W3 : W2;
        const float* __restrict__ bs = layer ? b3 : b2;

        float4 acc[NCOMP];
        #pragma unroll
        for (int c = 0; c < NCOMP; ++c) acc[c] = make_float4(0.f, 0.f, 0.f, 0.f);

        #pragma unroll 4
        for (int k = 0; k < HH; ++k) {
            const float4 wv = *(const float4*)(W + k * HH + j0);
            const float4 h0 = HB4(0, k, p);
            const float4 h1 = HB4(1, k, p);
            const float4 h2 = HB4(2, k, p);
            F4(acc[0], h0.x) F4(acc[1], h0.y) F4(acc[2],  h0.z) F4(acc[3],  h0.w)
            F4(acc[4], h1.x) F4(acc[5], h1.y) F4(acc[6],  h1.z) F4(acc[7],  h1.w)
            F4(acc[8], h2.x) F4(acc[9], h2.y) F4(acc[10], h2.z) F4(acc[11], h2.w)
        }
        __syncthreads();   // everyone done reading hb4
        COMPOSE(x, 0);
        COMPOSE(y, 1);
        COMPOSE(z, 2);
        COMPOSE(w, 3);
        __syncthreads();   // new hb4 ready
    }

    // ---------------- output layer (64 -> 1), 12 comps x 16 points ----------------
    if (tid < PTILE * NCOMP) {
        const int p2 = tid & 15;
        const int c2 = tid >> 4;   // 0..11
        const int cg = c2 >> 2, ce = c2 & 3;
        const float* hbf = (const float*)hb4;
        float s = 0.f;
        #pragma unroll 8
        for (int k = 0; k < HH; ++k)
            s = fmaf(hbf[((cg * HH + k) * PTILE + p2) * 4 + ce], Wo[k], s);
        ubuf[p2 * NCOMP + c2] = s;
    }
    __syncthreads();

    // ---------------- residual per point ----------------
    if (tid < PTILE) {
        const int pp = tid;
        const float* u = &ubuf[pp * NCOMP];
        const int gIdx = blockIdx.x * PTILE + pp;
        const float x = pts[2 * gIdx];
        const float t = pts[2 * gIdx + 1];

        const float D   = u[0] - u[6] - u[7];       // u - u(1,t) - u_x(1,t)
        const float Dx  = u[1];
        const float Dt  = u[2] - u[8] - u[9];
        const float Dxx = u[3];
        const float Dxt = u[4];
        const float Dtt = u[5] - u[10] - u[11];

        const float s  = sinf(PI_F * t);
        const float cc = cosf(PI_F * t);
        const float A  = t * t - t,  Ap = 2.f * t - 1.f;
        const float B  = x * x - x,  Bp = 2.f * x - 1.f;

        const float psi    = 2.f * x * s + A * B * D;
        const float psi_x  = 2.f * s + A * (Bp * D + B * Dx);
        const float psi_xx = A * (2.f * D + 2.f * Bp * Dx + B * Dxx);
        const float psi_xt = 2.f * PI_F * cc + Ap * (Bp * D + B * Dx)
                           + A * (Bp * Dt + B * Dxt);
        const float psi_tt = -2.f * PI_F * PI_F * x * s + 2.f * B * D
                           + 2.f * Ap * B * Dt + A * B * Dtt;

        const float forcing = s * (2.f - PI_F * PI_F * x * x + 2.f * x * x * x * s);
        const float res = psi_xx + 2.f * psi_xt + psi_tt + psi * psi_x - forcing;
        rbuf[pp] = fabsf(res);
    }
    __syncthreads();

    if (tid == 0) {
        float s = 0.f;
        #pragma unroll
        for (int i = 0; i < PTILE; ++i) s += rbuf[i];
        partial[blockIdx.x] = s;
    }
}

__global__ __launch_bounds__(256) void pinn_reduce(
    const float* __restrict__ partial, float* __restrict__ out,
    int nblocks, float invN)
{
    __shared__ float sd[256];
    float s = 0.f;
    for (int i = threadIdx.x; i < nblocks; i += 256) s += partial[i];
    sd[threadIdx.x] = s;
    __syncthreads();
    #pragma unroll
    for (int off = 128; off > 0; off >>= 1) {
        if (threadIdx.x < off) sd[threadIdx.x] += sd[threadIdx.x + off];
        __syncthreads();
    }
    if (threadIdx.x == 0) out[0] = sd[0] * invN;
}

extern "C" void kernel_launch(void* const* d_in, const int* in_sizes, int n_in,
                              void* d_out, int out_size, void* d_ws, size_t ws_size,
                              hipStream_t stream)
{
    const float* pts = (const float*)d_in[0];
    const float* W1  = (const float*)d_in[1];
    const float* b1  = (const float*)d_in[2];
    const float* W2  = (const float*)d_in[3];
    const float* b2  = (const float*)d_in[4];
    const float* W3  = (const float*)d_in[5];
    const float* b3  = (const float*)d_in[6];
    const float* Wo  = (const float*)d_in[7];
    // d_in[8] = bo: cancels in (u - u(1,t)) and has zero derivative.

    const int nPts    = in_sizes[0] / 2;          // 262144
    const int nBlocks = nPts / PTILE;             // 16384

    float* partial = (float*)d_ws;                // nBlocks * 4 B = 64 KB

    pinn_main<<<nBlocks, 256, 0, stream>>>(pts, W1, b1, W2, b2, W3, b3, Wo, partial);
    pinn_reduce<<<1, 256, 0, stream>>>(partial, (float*)d_out, nBlocks,
                                       1.f / (float)nPts);
}

// Round 3
// 300.014 us; speedup vs baseline: 2.6354x; 2.2714x over previous
//
#include <hip/hip_runtime.h>
#include <math.h>

typedef _Float16 half_t;
typedef half_t half8 __attribute__((ext_vector_type(8)));
typedef float f32x4 __attribute__((ext_vector_type(4)));

#define PI_F 3.14159265358979323846f

// J LDS layout: 192 rows (m = comp*16 + point) x 64 half cols (k = neuron).
// Row = 8 granules of 8 halves (16B); granule column rotated by
// s(m) = (m + m>>3) & 7 so the 16 rows of an A-fragment read map to
// distinct-ish bank groups (plain row-major would be a 16-way conflict).
__device__ __forceinline__ int swidx(int m, int col) {
    const int s = (m + (m >> 3)) & 7;
    return m * 64 + ((((col >> 3) + s) & 7) << 3) + (col & 7);
}

__global__ __launch_bounds__(512) void pinn_main(
    const float* __restrict__ pts,
    const float* __restrict__ W1, const float* __restrict__ b1,
    const float* __restrict__ b2, const float* __restrict__ b3,
    const half_t* __restrict__ wsH,    // Wt2 @0, Wt3 @4096, Wo @8192 (half idx)
    float* __restrict__ partial)
{
    __shared__ half_t J[2][192 * 64];   // 2 units x 24 KB
    __shared__ float rbuf[8];

    const int tid  = threadIdx.x;
    const int unit = tid >> 8;          // 16-point unit (4 waves each)
    const int l    = tid & 63;
    const int w    = (tid >> 6) & 3;    // wave within unit = N-tile
    const int q    = l >> 4;
    const int i    = l & 15;
    const int j    = w * 16 + i;        // output-neuron column owned
    half_t* Jl = J[unit];

    const int pbase = blockIdx.x * 32 + unit * 16;

    // points p = q*4 + r live in this lane's registers
    float px[4], pt[4];
    #pragma unroll
    for (int r = 0; r < 4; ++r) {
        const float2 xy = *(const float2*)(pts + 2 * (pbase + q * 4 + r));
        px[r] = xy.x; pt[r] = xy.y;
    }

    // ---------------- layer 1 (2 -> 64), jets written to J ----------------
    {
        const float w0 = W1[j], w1 = W1[64 + j], bb = b1[j];
        #pragma unroll
        for (int r = 0; r < 4; ++r) {
            const int p = q * 4 + r;
            float o[12];
            {   // interior jet at (x,t)
                const float zv = fmaf(px[r], w0, fmaf(pt[r], w1, bb));
                const float a  = tanhf(zv);
                const float d1 = 1.f - a * a;
                const float d2 = -2.f * a * d1;
                o[0] = a; o[1] = d1 * w0; o[2] = d1 * w1;
                o[3] = d2 * w0 * w0; o[4] = d2 * w0 * w1; o[5] = d2 * w1 * w1;
            }
            {   // boundary jet at (1,t)
                const float zv = w0 + fmaf(pt[r], w1, bb);
                const float a  = tanhf(zv);
                const float d1 = 1.f - a * a;
                const float d2 = -2.f * a * d1;
                const float d3 = -2.f * (d1 * d1 + a * d2);
                o[6] = a; o[7] = d1 * w0; o[8] = d1 * w1;
                o[9] = d2 * w0 * w1; o[10] = d2 * w1 * w1; o[11] = d3 * w0 * w1 * w1;
            }
            #pragma unroll
            for (int c = 0; c < 12; ++c)
                Jl[swidx(c * 16 + p, j)] = (half_t)o[c];
        }
    }

    // ---------------- hidden layers 2,3: MFMA jet-GEMM + compose ----------------
    #pragma unroll 1
    for (int layer = 0; layer < 2; ++layer) {
        const half_t* Wt = wsH + layer * 4096;   // [n][k] f16
        const float*  bs = layer ? b3 : b2;

        // B-fragments from global (L1-resident): B[k][n], n = j, k-chunk by q
        const half8 bf0 = *(const half8*)(Wt + j * 64 + q * 8);
        const half8 bf1 = *(const half8*)(Wt + j * 64 + 32 + q * 8);

        __syncthreads();   // J ready

        f32x4 acc[12];
        #pragma unroll
        for (int mt = 0; mt < 12; ++mt) {
            const int m = mt * 16 + i;
            const half8 a0 = *(const half8*)(Jl + swidx(m, q * 8));
            const half8 a1 = *(const half8*)(Jl + swidx(m, 32 + q * 8));
            f32x4 z = {0.f, 0.f, 0.f, 0.f};
            z = __builtin_amdgcn_mfma_f32_16x16x32_f16(a0, bf0, z, 0, 0, 0);
            z = __builtin_amdgcn_mfma_f32_16x16x32_f16(a1, bf1, z, 0, 0, 0);
            acc[mt] = z;
        }

        __syncthreads();   // all reads of J done

        // lane holds Z[c][p=q*4+r][j] in acc[c][r] -> tanh jet composition
        const float bj = bs[j];
        #pragma unroll
        for (int r = 0; r < 4; ++r) {
            const int p = q * 4 + r;
            const float zv = acc[0][r] + bj, zx = acc[1][r], zt = acc[2][r];
            const float zxx = acc[3][r], zxt = acc[4][r], ztt = acc[5][r];
            const float a  = tanhf(zv);
            const float d1 = 1.f - a * a;
            const float d2 = -2.f * a * d1;
            const float zvB = acc[6][r] + bj, zxB = acc[7][r], ztB = acc[8][r];
            const float zxtB = acc[9][r], zttB = acc[10][r], zxttB = acc[11][r];
            const float aB = tanhf(zvB);
            const float e1 = 1.f - aB * aB;
            const float e2 = -2.f * aB * e1;
            const float e3 = -2.f * (e1 * e1 + aB * e2);
            float o[12];
            o[0] = a;
            o[1] = d1 * zx;
            o[2] = d1 * zt;
            o[3] = fmaf(d2 * zx, zx, d1 * zxx);
            o[4] = fmaf(d2 * zx, zt, d1 * zxt);
            o[5] = fmaf(d2 * zt, zt, d1 * ztt);
            o[6] = aB;
            o[7] = e1 * zxB;
            o[8] = e1 * ztB;
            o[9]  = fmaf(e2 * zxB, ztB, e1 * zxtB);
            o[10] = fmaf(e2 * ztB, ztB, e1 * zttB);
            o[11] = e3 * zxB * ztB * ztB + e2 * (2.f * zxtB * ztB + zxB * zttB)
                  + e1 * zxttB;
            #pragma unroll
            for (int c = 0; c < 12; ++c)
                Jl[swidx(c * 16 + p, j)] = (half_t)o[c];
        }
    }

    __syncthreads();   // J3 ready

    // ---------------- output GEMV (Wo in B col 0) + residual ----------------
    if (w == 0) {
        const half_t* WoH = wsH + 8192;
        half8 c0 = {0, 0, 0, 0, 0, 0, 0, 0};
        half8 c1 = {0, 0, 0, 0, 0, 0, 0, 0};
        if (i == 0) {
            c0 = *(const half8*)(WoH + q * 8);
            c1 = *(const half8*)(WoH + 32 + q * 8);
        }

        f32x4 acc[12];
        #pragma unroll
        for (int mt = 0; mt < 12; ++mt) {
            const int m = mt * 16 + i;
            const half8 a0 = *(const half8*)(Jl + swidx(m, q * 8));
            const half8 a1 = *(const half8*)(Jl + swidx(m, 32 + q * 8));
            f32x4 z = {0.f, 0.f, 0.f, 0.f};
            z = __builtin_amdgcn_mfma_f32_16x16x32_f16(a0, c0, z, 0, 0, 0);
            z = __builtin_amdgcn_mfma_f32_16x16x32_f16(a1, c1, z, 0, 0, 0);
            acc[mt] = z;
        }

        if (i == 0) {   // lanes 0,16,32,48 hold u[c] for p = q*4 + r
            float sum4 = 0.f;
            #pragma unroll
            for (int r = 0; r < 4; ++r) {
                const float x = px[r], t = pt[r];
                const float D   = acc[0][r] - acc[6][r] - acc[7][r];
                const float Dx  = acc[1][r];
                const float Dt  = acc[2][r] - acc[8][r] - acc[9][r];
                const float Dxx = acc[3][r];
                const float Dxt = acc[4][r];
                const float Dtt = acc[5][r] - acc[10][r] - acc[11][r];

                const float s  = sinf(PI_F * t);
                const float cc = cosf(PI_F * t);
                const float A  = t * t - t,  Ap = 2.f * t - 1.f;
                const float B  = x * x - x,  Bp = 2.f * x - 1.f;

                const float psi    = 2.f * x * s + A * B * D;
                const float psi_x  = 2.f * s + A * (Bp * D + B * Dx);
                const float psi_xx = A * (2.f * D + 2.f * Bp * Dx + B * Dxx);
                const float psi_xt = 2.f * PI_F * cc + Ap * (Bp * D + B * Dx)
                                   + A * (Bp * Dt + B * Dxt);
                const float psi_tt = -2.f * PI_F * PI_F * x * s + 2.f * B * D
                                   + 2.f * Ap * B * Dt + A * B * Dtt;

                const float forcing = s * (2.f - PI_F * PI_F * x * x
                                           + 2.f * x * x * x * s);
                const float res = psi_xx + 2.f * psi_xt + psi_tt
                                + psi * psi_x - forcing;
                sum4 += fabsf(res);
            }
            rbuf[unit * 4 + q] = sum4;
        }
    }
    __syncthreads();

    if (tid == 0) {
        float s = 0.f;
        #pragma unroll
        for (int k2 = 0; k2 < 8; ++k2) s += rbuf[k2];
        partial[blockIdx.x] = s;
    }
}

__global__ __launch_bounds__(256) void pinn_prep(
    const float* __restrict__ W2, const float* __restrict__ W3,
    const float* __restrict__ Wo, half_t* __restrict__ wsH)
{
    const int tid = threadIdx.x;
    for (int idx = tid; idx < 4096; idx += 256) {
        const int n = idx >> 6, k = idx & 63;
        wsH[idx]        = (half_t)W2[k * 64 + n];   // Wt2[n][k]
        wsH[4096 + idx] = (half_t)W3[k * 64 + n];   // Wt3[n][k]
    }
    if (tid < 64) wsH[8192 + tid] = (half_t)Wo[tid];
}

__global__ __launch_bounds__(256) void pinn_reduce(
    const float* __restrict__ partial, float* __restrict__ out,
    int nblocks, float invN)
{
    __shared__ float sd[256];
    float s = 0.f;
    for (int i = threadIdx.x; i < nblocks; i += 256) s += partial[i];
    sd[threadIdx.x] = s;
    __syncthreads();
    #pragma unroll
    for (int off = 128; off > 0; off >>= 1) {
        if (threadIdx.x < off) sd[threadIdx.x] += sd[threadIdx.x + off];
        __syncthreads();
    }
    if (threadIdx.x == 0) out[0] = sd[0] * invN;
}

extern "C" void kernel_launch(void* const* d_in, const int* in_sizes, int n_in,
                              void* d_out, int out_size, void* d_ws, size_t ws_size,
                              hipStream_t stream)
{
    const float* pts = (const float*)d_in[0];
    const float* W1  = (const float*)d_in[1];
    const float* b1  = (const float*)d_in[2];
    const float* W2  = (const float*)d_in[3];
    const float* b2  = (const float*)d_in[4];
    const float* W3  = (const float*)d_in[5];
    const float* b3  = (const float*)d_in[6];
    const float* Wo  = (const float*)d_in[7];
    // d_in[8] = bo: cancels in (u - u(1,t)) and has zero derivative.

    const int nPts    = in_sizes[0] / 2;          // 262144
    const int nBlocks = nPts / 32;                // 8192 (32 points/block)

    half_t* wsH    = (half_t*)d_ws;                       // 33,024 B of weights
    float*  partial = (float*)((char*)d_ws + 32768);      // 32 KB of partials

    pinn_prep<<<1, 256, 0, stream>>>(W2, W3, Wo, wsH);
    pinn_main<<<nBlocks, 512, 0, stream>>>(pts, W1, b1, b2, b3, wsH, partial);
    pinn_reduce<<<1, 256, 0, stream>>>(partial, (float*)d_out, nBlocks,
                                       1.f / (float)nPts);
}